// Round 3
// baseline (445.418 us; speedup 1.0000x reference)
//
#include <hip/hip_runtime.h>
#include <hip/hip_cooperative_groups.h>
#include <math.h>

namespace cg = cooperative_groups;

#define B 4
#define N 256
#define DIN 4
#define D 64
#define NH 4
#define NL 2
#define DH 16

constexpr float EPS = 1e-5f;
constexpr float SLOPE = 0.01f;

// ---------------------------------------------------------------------------
// Direct global->LDS DMA staging: 64 lanes x 16B per wave per call.
// LDS dest must be wave-uniform base + lane*16. Drained by the next barrier.
// ---------------------------------------------------------------------------
template <int NF4>
__device__ __forceinline__ void stage(float* dst, const float* src, int t) {
    int lane = t & 63, w = t >> 6;
#pragma unroll
    for (int i0 = 0; i0 < NF4; i0 += 512) {
        int base = i0 + w * 64;
        __builtin_amdgcn_global_load_lds(
            (const __attribute__((address_space(1))) void*)(src + 4 * (base + lane)),
            (__attribute__((address_space(3))) void*)(dst + 4 * base),
            16, 0, 0);
    }
}

// ---------------------------------------------------------------------------
// Single cooperative mega-kernel. 256 blocks x 512 threads, 1 block/CU.
// Block cb owns tokens cb*4 .. cb*4+3 in every token-mapped phase, so h, q,
// and intermediate x never touch global memory. Only rs, BN stats, and K/V
// (double-buffered k0/v0 -> k1/v1, fixing the old in-place race) cross
// blocks, guarded by grid.sync().
// ---------------------------------------------------------------------------
__global__ void __launch_bounds__(512, 2) k_fused(
    const float* __restrict__ feature, const float* __restrict__ W1,
    const float* __restrict__ b1, const float* __restrict__ mw,
    const float* __restrict__ mb, const float* __restrict__ bn_g,
    const float* __restrict__ bn_b,
    const float* __restrict__ Wq, const float* __restrict__ bq,
    const float* __restrict__ Wk, const float* __restrict__ bk,
    const float* __restrict__ Wv, const float* __restrict__ bv,
    const float* __restrict__ Wo, const float* __restrict__ bo,
    const float* __restrict__ ln1g, const float* __restrict__ ln1b,
    const float* __restrict__ Wff1, const float* __restrict__ bff1,
    const float* __restrict__ Wff2, const float* __restrict__ bff2,
    const float* __restrict__ ln2g, const float* __restrict__ ln2b,
    float* __restrict__ rs, float* __restrict__ bnacc,
    float* __restrict__ k0, float* __restrict__ v0,
    float* __restrict__ k1, float* __restrict__ v1,
    float* __restrict__ xout)
{
    __shared__ __align__(16) float WA[3 * D * D];          // 48KB: Wq|Wk|Wv (layer l)
    __shared__ __align__(16) float WC[D * D + 4 * D * D];  // 80KB: Wo|Wff1|Wff2 (layer l)
    __shared__ __align__(16) float qsh[4 * D];             // Q tile (block-local)
    __shared__ __align__(16) float attS[4 * D];            // x tile / merged attn out
    __shared__ __align__(16) float xs1[4 * D];
    __shared__ __align__(16) float f1s[4 * 2 * D];
    __shared__ __align__(16) float pp[8 * 192];            // split-K partials
    __shared__ __align__(16) float attO[2][4 * D];
    __shared__ float attM[2][16], attL[2][16];
    __shared__ float rsP[32];
    __shared__ float part[8][10];
    __shared__ float gacc[20];
    __shared__ float hsm[4][D];

    cg::grid_group grid = cg::this_grid();
    int t = threadIdx.x;
    int lane = t & 63, w = t >> 6;
    int cb = blockIdx.x;
    int b = cb >> 6, q0 = (cb & 63) * 4;

    // ---- entry: register prefetch for P1/P2 BEFORE staging, so waiting on
    //      these does not drain the DMA queue ----
    int r_ = w & 3, mh_ = w >> 2;
    int bi = cb * 4 + r_;
    const float4* fbP1 = (const float4*)feature + (size_t)bi * N;
    float4 fP1[2];
    fP1[0] = fbP1[lane + 64 * (mh_ * 2 + 0)];
    fP1[1] = fbP1[lane + 64 * (mh_ * 2 + 1)];
    int iP2 = t & 255, jhP2 = t >> 8;
    const float4* fbP2 = (const float4*)feature + ((size_t)(b * N + iP2) * N + q0 + jhP2 * 2);
    float4 fP2[2];
    fP2[0] = fbP2[0];
    fP2[1] = fbP2[1];
    float w1v[4];
#pragma unroll
    for (int kk = 0; kk < 4; ++kk) w1v[kk] = W1[kk * D + lane];
    float b1v = b1[lane];
    float mwv4[4];
#pragma unroll
    for (int n = 0; n < 4; ++n) mwv4[n] = mw[n * D + lane];

    // ---- stage layer-0 weights into LDS (lands by P1's barrier) ----
    stage<1024>(WA, Wq, t);
    stage<1024>(WA + 4096, Wk, t);
    stage<1024>(WA + 8192, Wv, t);
    stage<1024>(WC, Wo, t);
    stage<2048>(WC + 4096, Wff1, t);
    stage<2048>(WC + 12288, Wff2, t);

    if (cb == 0 && t < 128) bnacc[t] = 0.f;

    // ---- M (4x4) and C (4) attention-score projection, in registers via
    //      wave shuffle-reduce (every wave holds a full copy) ----
    float Mreg[16], Creg[4];
#pragma unroll
    for (int n = 0; n < 4; ++n) {
        float mwv = mwv4[n];
        float p0 = w1v[0] * mwv, p1 = w1v[1] * mwv;
        float p2 = w1v[2] * mwv, p3 = w1v[3] * mwv;
        float pc = b1v * mwv;
#pragma unroll
        for (int off = 32; off > 0; off >>= 1) {
            p0 += __shfl_xor(p0, off); p1 += __shfl_xor(p1, off);
            p2 += __shfl_xor(p2, off); p3 += __shfl_xor(p3, off);
            pc += __shfl_xor(pc, off);
        }
        Mreg[n * 4 + 0] = p0; Mreg[n * 4 + 1] = p1;
        Mreg[n * 4 + 2] = p2; Mreg[n * 4 + 3] = p3;
        Creg[n] = pc + mb[n];
    }

    // ---- P1: rowsum. wave = (row r_, m-half mh_), lane owns 2 j's ----
    {
        float sn[4] = {0.f, 0.f, 0.f, 0.f};
#pragma unroll
        for (int mm = 0; mm < 2; ++mm) {
            float4 f = fP1[mm];
#pragma unroll
            for (int n = 0; n < 4; ++n) {
                float s = Creg[n] + f.x * Mreg[n*4+0] + f.y * Mreg[n*4+1]
                                  + f.z * Mreg[n*4+2] + f.w * Mreg[n*4+3];
                s = (s >= 0.f) ? s : SLOPE * s;
                sn[n] += __expf(s);
            }
        }
#pragma unroll
        for (int n = 0; n < 4; ++n)
#pragma unroll
            for (int off = 32; off > 0; off >>= 1) sn[n] += __shfl_xor(sn[n], off);
        if (lane == 0) {
#pragma unroll
            for (int n = 0; n < 4; ++n) rsP[w * 4 + n] = sn[n];
        }
        __syncthreads();     // also drains weight staging
        if (t < 16) {
            int rr = t >> 2, n = t & 3;
            rs[(size_t)(cb * 4 + rr) * 4 + n] = rsP[rr * 4 + n] + rsP[(rr + 4) * 4 + n];
        }
    }
    __threadfence();
    grid.sync();   // rs complete

    // ---- P2: aggregate + h-proj (LDS only) + BN partials ----
    {
        float4 r4 = *(const float4*)(rs + (size_t)(b * N + iP2) * 4);
        float rinv[4] = {1.f / r4.x, 1.f / r4.y, 1.f / r4.z, 1.f / r4.w};
        float acc[2][5];
#pragma unroll
        for (int jj = 0; jj < 2; ++jj) {
            float wbar = 0.f;
#pragma unroll
            for (int n = 0; n < 4; ++n) {
                float s = Creg[n] + fP2[jj].x * Mreg[n*4+0] + fP2[jj].y * Mreg[n*4+1]
                                  + fP2[jj].z * Mreg[n*4+2] + fP2[jj].w * Mreg[n*4+3];
                s = (s >= 0.f) ? s : SLOPE * s;
                wbar += __expf(s) * rinv[n];
            }
            wbar *= 0.25f;
            acc[jj][0] = wbar * fP2[jj].x; acc[jj][1] = wbar * fP2[jj].y;
            acc[jj][2] = wbar * fP2[jj].z; acc[jj][3] = wbar * fP2[jj].w;
            acc[jj][4] = wbar;
        }
#pragma unroll
        for (int jj = 0; jj < 2; ++jj)
#pragma unroll
            for (int c = 0; c < 5; ++c)
#pragma unroll
                for (int off = 32; off > 0; off >>= 1) acc[jj][c] += __shfl_xor(acc[jj][c], off);
        if (lane == 0) {
#pragma unroll
            for (int jj = 0; jj < 2; ++jj)
#pragma unroll
                for (int c = 0; c < 5; ++c) part[w][jj * 5 + c] = acc[jj][c];
        }
        __syncthreads();
        if (t < 20) {
            int jj = t / 5, c = t - jj * 5;
            int g = jj >> 1, jjl = jj & 1;
            gacc[t] = part[g*4+0][jjl*5+c] + part[g*4+1][jjl*5+c]
                    + part[g*4+2][jjl*5+c] + part[g*4+3][jjl*5+c];
        }
        __syncthreads();
        if (t < 256) {   // wave w = token q0+w, lane = channel
            float hv = gacc[w * 5 + 4] * b1v;
#pragma unroll
            for (int kk = 0; kk < 4; ++kk) hv += gacc[w * 5 + kk] * w1v[kk];
            hsm[w][lane] = hv;
        }
        __syncthreads();
        if (t < 64) {
            float s = hsm[0][lane] + hsm[1][lane] + hsm[2][lane] + hsm[3][lane];
            float sq = hsm[0][lane]*hsm[0][lane] + hsm[1][lane]*hsm[1][lane]
                     + hsm[2][lane]*hsm[2][lane] + hsm[3][lane]*hsm[3][lane];
            atomicAdd(bnacc + lane, s);
            atomicAdd(bnacc + D + lane, sq);
        }
    }
    __threadfence();
    grid.sync();   // bnacc complete

    // ---- P3: BN finalize + QKV layer 0 (wave = (tok4, kh), split-K) ----
    float xv;
    {
        int tok4 = w & 3, kh = w >> 2;
        int token = q0 + tok4;
        int ch = lane;
        float mean = bnacc[ch] * (1.0f / (B * N));
        float var = bnacc[D + ch] * (1.0f / (B * N)) - mean * mean;
        float inv = rsqrtf(var + EPS);
        float xvv = bn_g[ch] * (hsm[tok4][ch] - mean) * inv + bn_b[ch];
        xv = xvv;
        if (kh == 0) attS[tok4 * D + ch] = xvv;
        __syncthreads();
        const float4* xr4 = (const float4*)(attS + tok4 * D + kh * 32);
        float aq0=0.f, aq1=0.f, ak0=0.f, ak1=0.f, av0=0.f, av1=0.f;
#pragma unroll
        for (int k4 = 0; k4 < 8; ++k4) {
            float4 xx = xr4[k4];
            int kk = kh * 32 + k4 * 4;
            aq0 += xx.x * WA[(kk+0)*D+ch] + xx.z * WA[(kk+2)*D+ch];
            aq1 += xx.y * WA[(kk+1)*D+ch] + xx.w * WA[(kk+3)*D+ch];
            ak0 += xx.x * WA[4096+(kk+0)*D+ch] + xx.z * WA[4096+(kk+2)*D+ch];
            ak1 += xx.y * WA[4096+(kk+1)*D+ch] + xx.w * WA[4096+(kk+3)*D+ch];
            av0 += xx.x * WA[8192+(kk+0)*D+ch] + xx.z * WA[8192+(kk+2)*D+ch];
            av1 += xx.y * WA[8192+(kk+1)*D+ch] + xx.w * WA[8192+(kk+3)*D+ch];
        }
        float* ppw = pp + w * 192;
        ppw[ch] = aq0 + aq1;
        ppw[64 + ch] = ak0 + ak1;
        ppw[128 + ch] = av0 + av1;
        __syncthreads();
        if (kh == 0) {
            int head = ch >> 4, dh = ch & (DH - 1);
            size_t oidx = (((size_t)(b * NH + head)) * N + (token & (N - 1))) * DH + dh;
            qsh[tok4 * D + ch] = bq[ch] + pp[tok4*192 + ch] + pp[(tok4+4)*192 + ch];
            k0[oidx] = bk[ch] + pp[tok4*192 + 64 + ch] + pp[(tok4+4)*192 + 64 + ch];
            v0[oidx] = bv[ch] + pp[tok4*192 + 128 + ch] + pp[(tok4+4)*192 + 128 + ch];
        }
    }
    __threadfence();
    grid.sync();   // k0/v0 complete

    // ---- layer body: attention (flash-split over key halves) + tail ----
    // stMode 0: restage WA <- {sA,sB,sC} (3x1024); 1: restage WC (1024,2048,2048)
    auto layer = [&](const float* kg, const float* vg,
                     const float* boP, const float* l1gP, const float* l1bP,
                     const float* bf1P, const float* bf2P,
                     const float* l2gP, const float* l2bP,
                     int stMode, const float* sA, const float* sB, const float* sC,
                     bool fuse, const float* bqnP, const float* bknP, const float* bvnP,
                     float* kOut, float* vOut, bool writeX) {
        int h_ = w & 3, half = w >> 2;
        int tok4 = h_, kh = half;
        int token = q0 + tok4;
        int ch = lane;
        int bh = b * NH + h_;
        const float* kb = kg + ((size_t)bh * N + half * 128) * DH;
        const float* vb = vg + ((size_t)bh * N + half * 128) * DH;
        float4 Kr[2][4], Vr[2][4];
#pragma unroll
        for (int j = 0; j < 2; ++j) {
            int key = lane + 64 * j;
#pragma unroll
            for (int c = 0; c < 4; ++c) {
                Kr[j][c] = *(const float4*)(kb + (size_t)key * DH + 4 * c);
                Vr[j][c] = *(const float4*)(vb + (size_t)key * DH + 4 * c);
            }
        }
        float bo_r = boP[ch], l1g = l1gP[ch], l1b = l1bP[ch];
        float bf1_r = bf1P[kh * D + ch];
        float bf2_r = bf2P[ch], l2g = l2gP[ch], l2b = l2bP[ch];
        float bq_r = 0.f, bk_r = 0.f, bv_r = 0.f;
        if (fuse) { bq_r = bqnP[ch]; bk_r = bknP[ch]; bv_r = bvnP[ch]; }

        // restage next weight region (issued after K/V loads; drains at the
        // attention-end barrier, long before first read)
        if (stMode == 0) {
            stage<1024>(WA, sA, t);
            stage<1024>(WA + 4096, sB, t);
            stage<1024>(WA + 8192, sC, t);
        } else {
            stage<1024>(WC, sA, t);
            stage<2048>(WC + 4096, sB, t);
            stage<2048>(WC + 12288, sC, t);
        }

        // partial flash attention over this wave's 128-key half, 4 queries
#pragma unroll
        for (int qq = 0; qq < 4; ++qq) {
            const float4* qp4 = (const float4*)(qsh + qq * D + h_ * DH);
            float4 qv[4] = {qp4[0], qp4[1], qp4[2], qp4[3]};
            float s0 = 0.f, s1 = 0.f;
#pragma unroll
            for (int c = 0; c < 4; ++c) {
                s0 += qv[c].x*Kr[0][c].x + qv[c].y*Kr[0][c].y + qv[c].z*Kr[0][c].z + qv[c].w*Kr[0][c].w;
                s1 += qv[c].x*Kr[1][c].x + qv[c].y*Kr[1][c].y + qv[c].z*Kr[1][c].z + qv[c].w*Kr[1][c].w;
            }
            float m = fmaxf(s0, s1);
#pragma unroll
            for (int off = 32; off > 0; off >>= 1) m = fmaxf(m, __shfl_xor(m, off));
            float p0 = __expf((s0 - m) * 0.25f);   // 1/sqrt(DH) folded in
            float p1 = __expf((s1 - m) * 0.25f);
            float lsum = p0 + p1;
#pragma unroll
            for (int off = 32; off > 0; off >>= 1) lsum += __shfl_xor(lsum, off);
            float o[DH];
#pragma unroll
            for (int c = 0; c < 4; ++c) {
                o[4*c+0] = p0 * Vr[0][c].x + p1 * Vr[1][c].x;
                o[4*c+1] = p0 * Vr[0][c].y + p1 * Vr[1][c].y;
                o[4*c+2] = p0 * Vr[0][c].z + p1 * Vr[1][c].z;
                o[4*c+3] = p0 * Vr[0][c].w + p1 * Vr[1][c].w;
            }
#pragma unroll
            for (int d = 0; d < DH; ++d)
#pragma unroll
                for (int off = 32; off > 0; off >>= 1) o[d] += __shfl_xor(o[d], off);
            if (lane == 0) {
#pragma unroll
                for (int d = 0; d < DH; ++d) attO[half][qq * D + h_ * DH + d] = o[d];
                attM[half][qq * 4 + h_] = m;
                attL[half][qq * 4 + h_] = lsum;
            }
        }
        __syncthreads();   // attO/M/L ready; restaged weights landed

        if (w < 4) {       // merge the two key halves (wave = query qq)
            int qq = w;
            int head = ch >> 4;
            float m0 = attM[0][qq*4+head], m1 = attM[1][qq*4+head];
            float l0 = attL[0][qq*4+head], l1 = attL[1][qq*4+head];
            float M = fmaxf(m0, m1);
            float e0 = __expf((m0 - M) * 0.25f);
            float e1 = __expf((m1 - M) * 0.25f);
            float rl = 1.f / (l0 * e0 + l1 * e1);
            attS[qq * D + ch] = (attO[0][qq*D+ch] * e0 + attO[1][qq*D+ch] * e1) * rl;
        }
        __syncthreads();

        // O-proj (split-K)
        float* ppw = pp + w * 192;
        {
            const float4* ar4 = (const float4*)(attS + tok4 * D + kh * 32);
            float a0=0.f, a1=0.f, a2=0.f, a3=0.f;
#pragma unroll
            for (int k4 = 0; k4 < 8; ++k4) {
                float4 av = ar4[k4];
                int kk = kh * 32 + k4 * 4;
                a0 += av.x * WC[(kk+0)*D+ch];
                a1 += av.y * WC[(kk+1)*D+ch];
                a2 += av.z * WC[(kk+2)*D+ch];
                a3 += av.w * WC[(kk+3)*D+ch];
            }
            ppw[ch] = (a0+a1)+(a2+a3);
        }
        __syncthreads();
        float oo = bo_r + pp[tok4*192 + ch] + pp[(tok4+4)*192 + ch];
        float r = xv + oo;
        float s1v = r, sq1 = r * r;
#pragma unroll
        for (int off = 32; off > 0; off >>= 1) {
            s1v += __shfl_xor(s1v, off);
            sq1 += __shfl_xor(sq1, off);
        }
        float mean1 = s1v * (1.0f / D);
        float var1 = sq1 * (1.0f / D) - mean1 * mean1;
        float x1 = l1g * (r - mean1) * rsqrtf(var1 + EPS) + l1b;
        if (kh == 0) xs1[tok4 * D + ch] = x1;
        __syncthreads();

        // FFN1 (split-K, both output halves)
        {
            const float4* xr4 = (const float4*)(xs1 + tok4 * D + kh * 32);
            float u0=0.f,u1=0.f,u2=0.f,u3=0.f, g0=0.f,g1=0.f,g2=0.f,g3=0.f;
#pragma unroll
            for (int k4 = 0; k4 < 8; ++k4) {
                float4 xx = xr4[k4];
                int kk = kh * 32 + k4 * 4;
                u0 += xx.x * WC[4096+(kk+0)*128+ch];
                u1 += xx.y * WC[4096+(kk+1)*128+ch];
                u2 += xx.z * WC[4096+(kk+2)*128+ch];
                u3 += xx.w * WC[4096+(kk+3)*128+ch];
                g0 += xx.x * WC[4096+(kk+0)*128+64+ch];
                g1 += xx.y * WC[4096+(kk+1)*128+64+ch];
                g2 += xx.z * WC[4096+(kk+2)*128+64+ch];
                g3 += xx.w * WC[4096+(kk+3)*128+64+ch];
            }
            ppw[ch] = (u0+u1)+(u2+u3);
            ppw[64+ch] = (g0+g1)+(g2+g3);
        }
        __syncthreads();
        f1s[tok4*128 + kh*64 + ch] =
            fmaxf(pp[tok4*192 + kh*64 + ch] + pp[(tok4+4)*192 + kh*64 + ch] + bf1_r, 0.f);
        __syncthreads();

        // FFN2 (split-K over 128)
        {
            const float4* fr4 = (const float4*)(f1s + tok4*128 + kh*64);
            float e0=0.f,e1=0.f,e2=0.f,e3=0.f;
#pragma unroll
            for (int k4 = 0; k4 < 16; ++k4) {
                float4 fv = fr4[k4];
                int kk = kh*64 + k4*4;
                e0 += fv.x * WC[12288+(kk+0)*D+ch];
                e1 += fv.y * WC[12288+(kk+1)*D+ch];
                e2 += fv.z * WC[12288+(kk+2)*D+ch];
                e3 += fv.w * WC[12288+(kk+3)*D+ch];
            }
            ppw[ch] = (e0+e1)+(e2+e3);
        }
        __syncthreads();
        float o2 = bf2_r + pp[tok4*192 + ch] + pp[(tok4+4)*192 + ch];
        float r2 = x1 + o2;
        float s2 = r2, sq2 = r2 * r2;
#pragma unroll
        for (int off = 32; off > 0; off >>= 1) {
            s2 += __shfl_xor(s2, off);
            sq2 += __shfl_xor(sq2, off);
        }
        float mean2 = s2 * (1.0f / D);
        float var2 = sq2 * (1.0f / D) - mean2 * mean2;
        float xnew = l2g * (r2 - mean2) * rsqrtf(var2 + EPS) + l2b;
        xv = xnew;
        if (writeX && kh == 0) xout[((size_t)b * N + token) * D + ch] = xnew;

        // fused next-layer QKV (block-local; q stays in LDS, k/v double-buffered)
        if (fuse) {
            if (kh == 0) attS[tok4 * D + ch] = xnew;
            __syncthreads();
            const float4* xr4 = (const float4*)(attS + tok4 * D + kh * 32);
            float aq0=0.f, aq1=0.f, ak0=0.f, ak1=0.f, av0=0.f, av1=0.f;
#pragma unroll
            for (int k4 = 0; k4 < 8; ++k4) {
                float4 xx = xr4[k4];
                int kk = kh * 32 + k4 * 4;
                aq0 += xx.x * WA[(kk+0)*D+ch] + xx.z * WA[(kk+2)*D+ch];
                aq1 += xx.y * WA[(kk+1)*D+ch] + xx.w * WA[(kk+3)*D+ch];
                ak0 += xx.x * WA[4096+(kk+0)*D+ch] + xx.z * WA[4096+(kk+2)*D+ch];
                ak1 += xx.y * WA[4096+(kk+1)*D+ch] + xx.w * WA[4096+(kk+3)*D+ch];
                av0 += xx.x * WA[8192+(kk+0)*D+ch] + xx.z * WA[8192+(kk+2)*D+ch];
                av1 += xx.y * WA[8192+(kk+1)*D+ch] + xx.w * WA[8192+(kk+3)*D+ch];
            }
            ppw[ch] = aq0 + aq1;
            ppw[64+ch] = ak0 + ak1;
            ppw[128+ch] = av0 + av1;
            __syncthreads();
            if (kh == 0) {
                int head = ch >> 4, dh = ch & (DH - 1);
                size_t oidx = (((size_t)(b * NH + head)) * N + (token & (N - 1))) * DH + dh;
                qsh[tok4 * D + ch] = bq_r + pp[tok4*192 + ch] + pp[(tok4+4)*192 + ch];
                kOut[oidx] = bk_r + pp[tok4*192 + 64 + ch] + pp[(tok4+4)*192 + 64 + ch];
                vOut[oidx] = bv_r + pp[tok4*192 + 128 + ch] + pp[(tok4+4)*192 + 128 + ch];
            }
        }
    };

    // ---- P4: layer 0 (restage WA with layer-1 QKV weights during attention)
    layer(k0, v0, bo, ln1g, ln1b, bff1, bff2, ln2g, ln2b,
          0, Wq + D * D, Wk + D * D, Wv + D * D,
          true, bq + D, bk + D, bv + D, k1, v1, false);
    __threadfence();
    grid.sync();   // k1/v1 complete

    // ---- P5: layer 1 (restage WC with layer-1 tail weights during attention)
    layer(k1, v1, bo + D, ln1g + D, ln1b + D, bff1 + 2 * D, bff2 + D,
          ln2g + D, ln2b + D,
          1, Wo + D * D, Wff1 + 2 * D * D, Wff2 + 2 * D * D,
          false, nullptr, nullptr, nullptr, nullptr, nullptr, true);
}

extern "C" void kernel_launch(void* const* d_in, const int* in_sizes, int n_in,
                              void* d_out, int out_size, void* d_ws, size_t ws_size,
                              hipStream_t stream) {
    const float* feature = (const float*)d_in[0];
    const float* W1   = (const float*)d_in[1];
    const float* b1   = (const float*)d_in[2];
    const float* mw   = (const float*)d_in[3];
    const float* mb   = (const float*)d_in[4];
    const float* bn_g = (const float*)d_in[5];
    const float* bn_b = (const float*)d_in[6];
    const float* Wq   = (const float*)d_in[7];
    const float* bq   = (const float*)d_in[8];
    const float* Wk   = (const float*)d_in[9];
    const float* bk   = (const float*)d_in[10];
    const float* Wv   = (const float*)d_in[11];
    const float* bv   = (const float*)d_in[12];
    const float* Wo   = (const float*)d_in[13];
    const float* bo   = (const float*)d_in[14];
    const float* ln1g = (const float*)d_in[15];
    const float* ln1b = (const float*)d_in[16];
    const float* Wff1 = (const float*)d_in[17];
    const float* bff1 = (const float*)d_in[18];
    const float* Wff2 = (const float*)d_in[19];
    const float* bff2 = (const float*)d_in[20];
    const float* ln2g = (const float*)d_in[21];
    const float* ln2b = (const float*)d_in[22];

    float* ws    = (float*)d_ws;
    float* rs    = ws;                     // B*N*NH = 4096
    float* bnacc = rs + B * N * NH;        // 128
    float* k0    = bnacc + 128;            // B*N*D
    float* v0    = k0 + B * N * D;
    float* k1    = v0 + B * N * D;
    float* v1    = k1 + B * N * D;
    float* xout  = (float*)d_out;

    void* args[] = {
        (void*)&feature, (void*)&W1, (void*)&b1, (void*)&mw, (void*)&mb,
        (void*)&bn_g, (void*)&bn_b,
        (void*)&Wq, (void*)&bq, (void*)&Wk, (void*)&bk, (void*)&Wv, (void*)&bv,
        (void*)&Wo, (void*)&bo, (void*)&ln1g, (void*)&ln1b,
        (void*)&Wff1, (void*)&bff1, (void*)&Wff2, (void*)&bff2,
        (void*)&ln2g, (void*)&ln2b,
        (void*)&rs, (void*)&bnacc, (void*)&k0, (void*)&v0, (void*)&k1, (void*)&v1,
        (void*)&xout
    };
    hipLaunchCooperativeKernel((const void*)k_fused, dim3(256), dim3(512),
                               args, 0, stream);
}

// Round 4
// 153.013 us; speedup vs baseline: 2.9110x; 2.9110x over previous
//
#include <hip/hip_runtime.h>
#include <math.h>

#define B 4
#define N 256
#define DIN 4
#define D 64
#define NH 4
#define NL 2
#define DH 16

constexpr float EPS = 1e-5f;
constexpr float SLOPE = 0.01f;

// ---------------------------------------------------------------------------
// P1: rowsum. grid 256, block 512 (8 waves, 2/SIMD).
// Wave w = (row r = w&3, m-half mh = w>>2): each wave covers 128 j's of row
// bi = cb*4+r; halves combine through LDS. Block 0 zero-inits BN accum.
// ---------------------------------------------------------------------------
__global__ void __launch_bounds__(512) k_rowsum(
    const float* __restrict__ feature, const float* __restrict__ W1,
    const float* __restrict__ b1, const float* __restrict__ mw,
    const float* __restrict__ mb, float* __restrict__ rs,
    float* __restrict__ bnacc /* [128]: macc|sacc */) {
    __shared__ float M[16];
    __shared__ float C[4];
    __shared__ float part[32];   // [8 waves][4 heads]
    int t = threadIdx.x;
    int lane = t & 63, w = t >> 6;
    int cb = blockIdx.x;
    if (cb == 0 && t < 128) bnacc[t] = 0.f;
    if (t < 16) {
        int n = t >> 2, kk = t & 3;
        float s = 0.f;
        for (int d = 0; d < D; ++d) s += W1[kk * D + d] * mw[n * D + d];
        M[t] = s;
    } else if (t < 20) {
        int n = t - 16;
        float s = mb[n];
        for (int d = 0; d < D; ++d) s += b1[d] * mw[n * D + d];
        C[n] = s;
    }
    __syncthreads();

    int r = w & 3, mh = w >> 2;
    int bi = cb * 4 + r;
    const float4* fb = (const float4*)(feature) + (size_t)bi * N;
    float sn[4] = {0.f, 0.f, 0.f, 0.f};
#pragma unroll
    for (int mm = 0; mm < 2; ++mm) {
        float4 f = fb[lane + 64 * (mh * 2 + mm)];
#pragma unroll
        for (int n = 0; n < 4; ++n) {
            float s = C[n] + f.x * M[n*4+0] + f.y * M[n*4+1] + f.z * M[n*4+2] + f.w * M[n*4+3];
            s = (s >= 0.f) ? s : SLOPE * s;
            sn[n] += __expf(s);
        }
    }
#pragma unroll
    for (int n = 0; n < 4; ++n)
#pragma unroll
        for (int off = 32; off > 0; off >>= 1) sn[n] += __shfl_xor(sn[n], off);
    if (lane == 0) {
#pragma unroll
        for (int n = 0; n < 4; ++n) part[w * 4 + n] = sn[n];
    }
    __syncthreads();
    if (t < 16) {
        int rr = t >> 2, n = t & 3;
        rs[((size_t)(cb * 4 + rr)) * 4 + n] = part[rr * 4 + n] + part[(rr + 4) * 4 + n];
    }
}

// ---------------------------------------------------------------------------
// P2: aggregate + h projection + BN partial sums (atomic).
// grid 256 (b = cb>>6, j0 = (cb&63)*4), block 512 (8 waves, 2/SIMD).
// Thread = (i = t&255, j-half jh = t>>8); each thread handles 2 j's.
// ---------------------------------------------------------------------------
__global__ void __launch_bounds__(512) k_aggregate(
    const float* __restrict__ feature, const float* __restrict__ W1,
    const float* __restrict__ b1, const float* __restrict__ mw,
    const float* __restrict__ mb, const float* __restrict__ rs,
    float* __restrict__ h, float* __restrict__ bnacc) {
    __shared__ float M[16];
    __shared__ float C[4];
    __shared__ float part[8][10];  // [wave][jjl*5+c]
    __shared__ float gacc[20];     // [jj][c]
    __shared__ float hs[4][D];
    int t = threadIdx.x;
    int lane = t & 63, w = t >> 6;
    int cb = blockIdx.x;
    if (t < 16) {
        int n = t >> 2, kk = t & 3;
        float s = 0.f;
        for (int d = 0; d < D; ++d) s += W1[kk * D + d] * mw[n * D + d];
        M[t] = s;
    } else if (t < 20) {
        int n = t - 16;
        float s = mb[n];
        for (int d = 0; d < D; ++d) s += b1[d] * mw[n * D + d];
        C[n] = s;
    }
    __syncthreads();

    int b = cb >> 6, j0 = (cb & 63) * 4;
    int i = t & 255, jh = t >> 8;
    const float4* fb = (const float4*)(feature) + ((size_t)(b * N + i) * N + j0 + jh * 2);
    float4 f[2];
    f[0] = fb[0];
    f[1] = fb[1];
    float4 r4 = *(const float4*)(rs + (size_t)(b * N + i) * 4);
    float rinv[4] = {1.f / r4.x, 1.f / r4.y, 1.f / r4.z, 1.f / r4.w};
    float acc[2][5];
#pragma unroll
    for (int jj = 0; jj < 2; ++jj) {
        float wbar = 0.f;
#pragma unroll
        for (int n = 0; n < 4; ++n) {
            float s = C[n] + f[jj].x * M[n*4+0] + f[jj].y * M[n*4+1] + f[jj].z * M[n*4+2] + f[jj].w * M[n*4+3];
            s = (s >= 0.f) ? s : SLOPE * s;
            wbar += __expf(s) * rinv[n];
        }
        wbar *= 0.25f;
        acc[jj][0] = wbar * f[jj].x; acc[jj][1] = wbar * f[jj].y;
        acc[jj][2] = wbar * f[jj].z; acc[jj][3] = wbar * f[jj].w;
        acc[jj][4] = wbar;
    }
#pragma unroll
    for (int jj = 0; jj < 2; ++jj)
#pragma unroll
        for (int c = 0; c < 5; ++c)
#pragma unroll
            for (int off = 32; off > 0; off >>= 1) acc[jj][c] += __shfl_xor(acc[jj][c], off);
    if (lane == 0) {
#pragma unroll
        for (int jj = 0; jj < 2; ++jj)
#pragma unroll
            for (int c = 0; c < 5; ++c) part[w][jj * 5 + c] = acc[jj][c];
    }
    __syncthreads();
    if (t < 20) {
        int jj = t / 5, c = t - jj * 5;
        int g = jj >> 1, jjl = jj & 1;
        gacc[t] = part[g*4+0][jjl*5+c] + part[g*4+1][jjl*5+c]
                + part[g*4+2][jjl*5+c] + part[g*4+3][jjl*5+c];
    }
    __syncthreads();
    if (t < 256) {   // wave w = token j0+w, lane = channel
        float hv = gacc[w * 5 + 4] * b1[lane];
#pragma unroll
        for (int kk = 0; kk < 4; ++kk) hv += gacc[w * 5 + kk] * W1[kk * D + lane];
        h[((size_t)(b * N + j0 + w)) * D + lane] = hv;
        hs[w][lane] = hv;
    }
    __syncthreads();
    if (t < 64) {
        float s = hs[0][lane] + hs[1][lane] + hs[2][lane] + hs[3][lane];
        float sq = hs[0][lane]*hs[0][lane] + hs[1][lane]*hs[1][lane]
                 + hs[2][lane]*hs[2][lane] + hs[3][lane]*hs[3][lane];
        atomicAdd(bnacc + lane, s);
        atomicAdd(bnacc + D + lane, sq);
    }
}

// ---------------------------------------------------------------------------
// P3: BN finalize + QKV layer 0. grid (B,N) = 1024 blocks x 256 thr (4 waves,
// 4 blocks/CU). Split-K-4 over waves; activations broadcast via __shfl;
// weights straight from global (L2-resident). No big LDS.
// ---------------------------------------------------------------------------
__global__ void __launch_bounds__(256, 4) k_qkv0(
    const float* __restrict__ h, const float* __restrict__ bnacc,
    const float* __restrict__ bn_g, const float* __restrict__ bn_b,
    const float* __restrict__ Wq, const float* __restrict__ bq,
    const float* __restrict__ Wk, const float* __restrict__ bk,
    const float* __restrict__ Wv, const float* __restrict__ bv,
    float* __restrict__ x, float* __restrict__ q,
    float* __restrict__ k, float* __restrict__ v) {
    __shared__ float pp[4][192];
    int t = threadIdx.x, lane = t & 63, w = t >> 6, ch = lane;
    int b = blockIdx.x, n = blockIdx.y;
    int token = b * N + n;
    float mean = bnacc[ch] * (1.0f / (B * N));
    float var = bnacc[D + ch] * (1.0f / (B * N)) - mean * mean;
    float inv = rsqrtf(var + EPS);
    float xv = bn_g[ch] * (h[(size_t)token * D + ch] - mean) * inv + bn_b[ch];
    if (w == 0) x[(size_t)token * D + ch] = xv;
    float aq = 0.f, ak = 0.f, av = 0.f;
#pragma unroll
    for (int i = 0; i < 16; ++i) {
        int kk = w * 16 + i;
        float xx = __shfl(xv, kk);
        aq += xx * Wq[kk * D + ch];
        ak += xx * Wk[kk * D + ch];
        av += xx * Wv[kk * D + ch];
    }
    pp[w][ch] = aq; pp[w][64 + ch] = ak; pp[w][128 + ch] = av;
    __syncthreads();
    if (w < 3) {
        int o = w * 64;
        float val = pp[0][o + ch] + pp[1][o + ch] + pp[2][o + ch] + pp[3][o + ch];
        int head = ch >> 4, dh = ch & (DH - 1);
        size_t oidx = (((size_t)(b * NH + head)) * N + n) * DH + dh;
        if (w == 0) q[oidx] = val + bq[ch];
        else if (w == 1) k[oidx] = val + bk[ch];
        else v[oidx] = val + bv[ch];
    }
}

// ---------------------------------------------------------------------------
// Layer tail: attention + O-proj + LN1 + FFN + LN2 (+ next-layer QKV).
// grid (B,N) = 1024 blocks x 256 thr, 4 blocks/CU (16 waves/CU).
// Attention: wave = head; K/V streamed from global in 64-key chunks (no
// register-resident K/V block, no spills). No softmax max-subtraction:
// scores are bounded |s|<~1 by construction, exp is exact-safe in fp32.
// Post phases: split-K-4 across waves; activations via __shfl broadcast;
// ping-pong pp buffers so each phase needs one barrier.
// ---------------------------------------------------------------------------
__global__ void __launch_bounds__(256, 4) k_layer(
    const float* __restrict__ q, const float* __restrict__ k,
    const float* __restrict__ v,
    const float* __restrict__ Wo, const float* __restrict__ bo,
    const float* __restrict__ ln1g, const float* __restrict__ ln1b,
    const float* __restrict__ Wff1, const float* __restrict__ bff1,
    const float* __restrict__ Wff2, const float* __restrict__ bff2,
    const float* __restrict__ ln2g, const float* __restrict__ ln2b,
    const float* __restrict__ Wqn, const float* __restrict__ bqn,
    const float* __restrict__ Wkn, const float* __restrict__ bkn,
    const float* __restrict__ Wvn, const float* __restrict__ bvn,
    float* __restrict__ qo, float* __restrict__ ko, float* __restrict__ vo,
    float* __restrict__ x) {
    __shared__ float attS[D];
    __shared__ float ppA[4][192];
    __shared__ float ppB[4][192];
    int t = threadIdx.x, lane = t & 63, w = t >> 6, ch = lane;
    int b = blockIdx.x, n = blockIdx.y;
    int token = b * N + n;
    size_t xidx = (size_t)token * D + ch;
    float xv = x[xidx];

    // ---- attention: wave = head w; stream K/V in 4 chunks of 64 keys ----
    int bh = b * NH + w;
    const float* qp = q + ((size_t)bh * N + n) * DH;
    float4 qv[4];
#pragma unroll
    for (int c = 0; c < 4; ++c) qv[c] = ((const float4*)qp)[c];
    const float* kb = k + (size_t)bh * N * DH;
    const float* vb = v + (size_t)bh * N * DH;
    float o[DH];
#pragma unroll
    for (int d = 0; d < DH; ++d) o[d] = 0.f;
    float l = 0.f;
#pragma unroll 2
    for (int cc = 0; cc < 4; ++cc) {
        int key = cc * 64 + lane;
        const float4* kp4 = (const float4*)(kb + (size_t)key * DH);
        const float4* vp4 = (const float4*)(vb + (size_t)key * DH);
        float4 Kc[4], Vc[4];
#pragma unroll
        for (int c = 0; c < 4; ++c) { Kc[c] = kp4[c]; Vc[c] = vp4[c]; }
        float s = 0.f;
#pragma unroll
        for (int c = 0; c < 4; ++c)
            s += qv[c].x * Kc[c].x + qv[c].y * Kc[c].y +
                 qv[c].z * Kc[c].z + qv[c].w * Kc[c].w;
        float p = __expf(s * 0.25f);   // 1/sqrt(DH) folded; no max-subtract
        l += p;
#pragma unroll
        for (int c = 0; c < 4; ++c) {
            o[4*c+0] += p * Vc[c].x;
            o[4*c+1] += p * Vc[c].y;
            o[4*c+2] += p * Vc[c].z;
            o[4*c+3] += p * Vc[c].w;
        }
    }
#pragma unroll
    for (int off = 32; off > 0; off >>= 1) l += __shfl_xor(l, off);
#pragma unroll
    for (int d = 0; d < DH; ++d)
#pragma unroll
        for (int off = 32; off > 0; off >>= 1) o[d] += __shfl_xor(o[d], off);
    float rl = 1.f / l;
    if (lane < DH) {
        float sel = o[0];
#pragma unroll
        for (int d = 1; d < DH; ++d) if (lane == d) sel = o[d];
        attS[w * DH + lane] = sel * rl;
    }
    __syncthreads();

    // ---- O-proj (split-K-4) -> ppA ----
    {
        float acc = 0.f;
#pragma unroll
        for (int i = 0; i < 16; ++i) {
            int kk = w * 16 + i;
            acc += attS[kk] * Wo[kk * D + ch];   // attS[kk]: uniform broadcast read
        }
        ppA[w][ch] = acc;
    }
    __syncthreads();
    float oo = bo[ch] + ppA[0][ch] + ppA[1][ch] + ppA[2][ch] + ppA[3][ch];
    float r = xv + oo;
    float s1 = r, sq1 = r * r;
#pragma unroll
    for (int off = 32; off > 0; off >>= 1) {
        s1 += __shfl_xor(s1, off);
        sq1 += __shfl_xor(sq1, off);
    }
    float mean1 = s1 * (1.0f / D);
    float var1 = sq1 * (1.0f / D) - mean1 * mean1;
    float x1 = ln1g[ch] * (r - mean1) * rsqrtf(var1 + EPS) + ln1b[ch];

    // ---- FFN1 (split-K-4) -> ppB ----
    {
        float u = 0.f, g = 0.f;
#pragma unroll
        for (int i = 0; i < 16; ++i) {
            int kk = w * 16 + i;
            float xx = __shfl(x1, kk);
            u += xx * Wff1[kk * 2 * D + ch];
            g += xx * Wff1[kk * 2 * D + D + ch];
        }
        ppB[w][ch] = u; ppB[w][64 + ch] = g;
    }
    __syncthreads();
    float f1lo = fmaxf(bff1[ch] + ppB[0][ch] + ppB[1][ch] + ppB[2][ch] + ppB[3][ch], 0.f);
    float f1hi = fmaxf(bff1[D + ch] + ppB[0][64+ch] + ppB[1][64+ch] + ppB[2][64+ch] + ppB[3][64+ch], 0.f);

    // ---- FFN2 (split-K-4 over 128) -> ppA ----
    {
        float src = (w < 2) ? f1lo : f1hi;
        int kb0 = (w & 1) * 32;
        float acc = 0.f;
#pragma unroll
        for (int i = 0; i < 32; ++i) {
            int kk = (w >> 1) * 64 + kb0 + i;   // 0..127 across waves
            float xx = __shfl(src, kb0 + i);
            acc += xx * Wff2[kk * D + ch];
        }
        ppA[w][ch] = acc;
    }
    __syncthreads();
    float o2 = bff2[ch] + ppA[0][ch] + ppA[1][ch] + ppA[2][ch] + ppA[3][ch];
    float r2 = x1 + o2;
    float s2 = r2, sq2 = r2 * r2;
#pragma unroll
    for (int off = 32; off > 0; off >>= 1) {
        s2 += __shfl_xor(s2, off);
        sq2 += __shfl_xor(sq2, off);
    }
    float mean2 = s2 * (1.0f / D);
    float var2 = sq2 * (1.0f / D) - mean2 * mean2;
    float xnew = ln2g[ch] * (r2 - mean2) * rsqrtf(var2 + EPS) + ln2b[ch];
    if (w == 0) x[xidx] = xnew;

    // ---- fused next-layer QKV (token-owned; K/V to double buffer) ----
    if (Wqn != nullptr) {
        float aq = 0.f, ak = 0.f, avv = 0.f;
#pragma unroll
        for (int i = 0; i < 16; ++i) {
            int kk = w * 16 + i;
            float xx = __shfl(xnew, kk);
            aq  += xx * Wqn[kk * D + ch];
            ak  += xx * Wkn[kk * D + ch];
            avv += xx * Wvn[kk * D + ch];
        }
        ppB[w][ch] = aq; ppB[w][64 + ch] = ak; ppB[w][128 + ch] = avv;
        __syncthreads();
        if (w < 3) {
            int off = w * 64;
            float val = ppB[0][off+ch] + ppB[1][off+ch] + ppB[2][off+ch] + ppB[3][off+ch];
            int head = ch >> 4, dh = ch & (DH - 1);
            size_t oidx = (((size_t)(b * NH + head)) * N + n) * DH + dh;
            if (w == 0) qo[oidx] = val + bqn[ch];
            else if (w == 1) ko[oidx] = val + bkn[ch];
            else vo[oidx] = val + bvn[ch];
        }
    }
}

extern "C" void kernel_launch(void* const* d_in, const int* in_sizes, int n_in,
                              void* d_out, int out_size, void* d_ws, size_t ws_size,
                              hipStream_t stream) {
    const float* feature = (const float*)d_in[0];
    const float* W1   = (const float*)d_in[1];
    const float* b1   = (const float*)d_in[2];
    const float* mw   = (const float*)d_in[3];
    const float* mb   = (const float*)d_in[4];
    const float* bn_g = (const float*)d_in[5];
    const float* bn_b = (const float*)d_in[6];
    const float* Wq   = (const float*)d_in[7];
    const float* bq   = (const float*)d_in[8];
    const float* Wk   = (const float*)d_in[9];
    const float* bk   = (const float*)d_in[10];
    const float* Wv   = (const float*)d_in[11];
    const float* bv   = (const float*)d_in[12];
    const float* Wo   = (const float*)d_in[13];
    const float* bo   = (const float*)d_in[14];
    const float* ln1g = (const float*)d_in[15];
    const float* ln1b = (const float*)d_in[16];
    const float* Wff1 = (const float*)d_in[17];
    const float* bff1 = (const float*)d_in[18];
    const float* Wff2 = (const float*)d_in[19];
    const float* bff2 = (const float*)d_in[20];
    const float* ln2g = (const float*)d_in[21];
    const float* ln2b = (const float*)d_in[22];

    float* ws    = (float*)d_ws;
    float* rs    = ws;                     // B*N*NH = 4096
    float* bnacc = rs + B * N * NH;        // 128
    float* h     = bnacc + 128;            // B*N*D
    float* q     = h + B * N * D;          // B*N*D
    float* k0    = q + B * N * D;
    float* v0    = k0 + B * N * D;
    float* k1    = v0 + B * N * D;
    float* v1    = k1 + B * N * D;
    float* x     = (float*)d_out;          // running (B,N,D) activation

    k_rowsum<<<256, 512, 0, stream>>>(feature, W1, b1, mw, mb, rs, bnacc);
    k_aggregate<<<256, 512, 0, stream>>>(feature, W1, b1, mw, mb, rs, h, bnacc);
    k_qkv0<<<dim3(B, N), 256, 0, stream>>>(h, bnacc, bn_g, bn_b,
                                           Wq, bq, Wk, bk, Wv, bv, x, q, k0, v0);
    // layer 0 (fused layer-1 QKV into q / k1 / v1), then layer 1
    k_layer<<<dim3(B, N), 256, 0, stream>>>(q, k0, v0,
        Wo, bo, ln1g, ln1b, Wff1, bff1, Wff2, bff2, ln2g, ln2b,
        Wq + (size_t)D * D, bq + D, Wk + (size_t)D * D, bk + D,
        Wv + (size_t)D * D, bv + D, q, k1, v1, x);
    k_layer<<<dim3(B, N), 256, 0, stream>>>(q, k1, v1,
        Wo + (size_t)D * D, bo + D, ln1g + D, ln1b + D,
        Wff1 + (size_t)D * 2 * D, bff1 + 2 * D,
        Wff2 + (size_t)2 * D * D, bff2 + D, ln2g + D, ln2b + D,
        nullptr, nullptr, nullptr, nullptr, nullptr, nullptr,
        nullptr, nullptr, nullptr, x);
}

// Round 5
// 147.741 us; speedup vs baseline: 3.0149x; 1.0357x over previous
//
#include <hip/hip_runtime.h>
#include <math.h>

#define B 4
#define N 256
#define DIN 4
#define D 64
#define NH 4
#define NL 2
#define DH 16

constexpr float EPS = 1e-5f;
constexpr float SLOPE = 0.01f;

// ---------------------------------------------------------------------------
// Register M/C projection: M[n][k] = sum_d W1[k][d]*mw[n][d]; C[n] = mb[n] +
// sum_d b1[d]*mw[n][d]. Computed redundantly per wave via butterfly reduce —
// no serial prologue, no LDS, no barrier.
// ---------------------------------------------------------------------------
__device__ __forceinline__ void mc_proj(
    const float* __restrict__ W1, const float* __restrict__ b1,
    const float* __restrict__ mw, const float* __restrict__ mb,
    int lane, float* Mreg /*16*/, float* Creg /*4*/) {
    float w1v[4];
#pragma unroll
    for (int kk = 0; kk < 4; ++kk) w1v[kk] = W1[kk * D + lane];
    float b1v = b1[lane];
#pragma unroll
    for (int n = 0; n < 4; ++n) {
        float mwv = mw[n * D + lane];
        float p0 = w1v[0] * mwv, p1 = w1v[1] * mwv;
        float p2 = w1v[2] * mwv, p3 = w1v[3] * mwv;
        float pc = b1v * mwv;
#pragma unroll
        for (int off = 32; off > 0; off >>= 1) {
            p0 += __shfl_xor(p0, off); p1 += __shfl_xor(p1, off);
            p2 += __shfl_xor(p2, off); p3 += __shfl_xor(p3, off);
            pc += __shfl_xor(pc, off);
        }
        Mreg[n * 4 + 0] = p0; Mreg[n * 4 + 1] = p1;
        Mreg[n * 4 + 2] = p2; Mreg[n * 4 + 3] = p3;
        Creg[n] = pc + mb[n];
    }
}

// ---------------------------------------------------------------------------
// P1: rowsum. grid 256, block 512 (8 waves). Wave w = (row r=w&3, half mh).
// ---------------------------------------------------------------------------
__global__ void __launch_bounds__(512) k_rowsum(
    const float* __restrict__ feature, const float* __restrict__ W1,
    const float* __restrict__ b1, const float* __restrict__ mw,
    const float* __restrict__ mb, float* __restrict__ rs,
    float* __restrict__ bnacc /* [128]: macc|sacc */) {
    __shared__ float part[32];   // [8 waves][4 heads]
    int t = threadIdx.x;
    int lane = t & 63, w = t >> 6;
    int cb = blockIdx.x;
    if (cb == 0 && t < 128) bnacc[t] = 0.f;

    int r = w & 3, mh = w >> 2;
    int bi = cb * 4 + r;
    const float4* fb = (const float4*)(feature) + (size_t)bi * N;
    float4 f0 = fb[lane + 64 * (mh * 2 + 0)];
    float4 f1 = fb[lane + 64 * (mh * 2 + 1)];

    float Mreg[16], Creg[4];
    mc_proj(W1, b1, mw, mb, lane, Mreg, Creg);

    float sn[4] = {0.f, 0.f, 0.f, 0.f};
#pragma unroll
    for (int mm = 0; mm < 2; ++mm) {
        float4 f = (mm == 0) ? f0 : f1;
#pragma unroll
        for (int n = 0; n < 4; ++n) {
            float s = Creg[n] + f.x * Mreg[n*4+0] + f.y * Mreg[n*4+1]
                              + f.z * Mreg[n*4+2] + f.w * Mreg[n*4+3];
            s = (s >= 0.f) ? s : SLOPE * s;
            sn[n] += __expf(s);
        }
    }
#pragma unroll
    for (int n = 0; n < 4; ++n)
#pragma unroll
        for (int off = 32; off > 0; off >>= 1) sn[n] += __shfl_xor(sn[n], off);
    if (lane == 0) {
#pragma unroll
        for (int n = 0; n < 4; ++n) part[w * 4 + n] = sn[n];
    }
    __syncthreads();
    if (t < 16) {
        int rr = t >> 2, n = t & 3;
        rs[((size_t)(cb * 4 + rr)) * 4 + n] = part[rr * 4 + n] + part[(rr + 4) * 4 + n];
    }
}

// ---------------------------------------------------------------------------
// P2: aggregate + h projection + BN partial sums. grid 256, block 512.
// Thread = (i = t&255, j-half jh = t>>8); each thread handles 2 j's.
// ---------------------------------------------------------------------------
__global__ void __launch_bounds__(512) k_aggregate(
    const float* __restrict__ feature, const float* __restrict__ W1,
    const float* __restrict__ b1, const float* __restrict__ mw,
    const float* __restrict__ mb, const float* __restrict__ rs,
    float* __restrict__ h, float* __restrict__ bnacc) {
    __shared__ float part[8][10];  // [wave][jjl*5+c]
    __shared__ float gacc[20];     // [jj][c]
    __shared__ float hs[4][D];
    int t = threadIdx.x;
    int lane = t & 63, w = t >> 6;
    int cb = blockIdx.x;

    int b = cb >> 6, j0 = (cb & 63) * 4;
    int i = t & 255, jh = t >> 8;
    const float4* fb = (const float4*)(feature) + ((size_t)(b * N + i) * N + j0 + jh * 2);
    float4 f[2];
    f[0] = fb[0];
    f[1] = fb[1];
    float4 r4 = *(const float4*)(rs + (size_t)(b * N + i) * 4);

    float Mreg[16], Creg[4];
    mc_proj(W1, b1, mw, mb, lane, Mreg, Creg);
    float w1v[4];
#pragma unroll
    for (int kk = 0; kk < 4; ++kk) w1v[kk] = W1[kk * D + lane];
    float b1v = b1[lane];

    float rinv[4] = {1.f / r4.x, 1.f / r4.y, 1.f / r4.z, 1.f / r4.w};
    float acc[2][5];
#pragma unroll
    for (int jj = 0; jj < 2; ++jj) {
        float wbar = 0.f;
#pragma unroll
        for (int n = 0; n < 4; ++n) {
            float s = Creg[n] + f[jj].x * Mreg[n*4+0] + f[jj].y * Mreg[n*4+1]
                              + f[jj].z * Mreg[n*4+2] + f[jj].w * Mreg[n*4+3];
            s = (s >= 0.f) ? s : SLOPE * s;
            wbar += __expf(s) * rinv[n];
        }
        wbar *= 0.25f;
        acc[jj][0] = wbar * f[jj].x; acc[jj][1] = wbar * f[jj].y;
        acc[jj][2] = wbar * f[jj].z; acc[jj][3] = wbar * f[jj].w;
        acc[jj][4] = wbar;
    }
#pragma unroll
    for (int jj = 0; jj < 2; ++jj)
#pragma unroll
        for (int c = 0; c < 5; ++c)
#pragma unroll
            for (int off = 32; off > 0; off >>= 1) acc[jj][c] += __shfl_xor(acc[jj][c], off);
    if (lane == 0) {
#pragma unroll
        for (int jj = 0; jj < 2; ++jj)
#pragma unroll
            for (int c = 0; c < 5; ++c) part[w][jj * 5 + c] = acc[jj][c];
    }
    __syncthreads();
    if (t < 20) {
        int jj = t / 5, c = t - jj * 5;
        int g = jj >> 1, jjl = jj & 1;
        gacc[t] = part[g*4+0][jjl*5+c] + part[g*4+1][jjl*5+c]
                + part[g*4+2][jjl*5+c] + part[g*4+3][jjl*5+c];
    }
    __syncthreads();
    if (t < 256) {   // wave w = token j0+w, lane = channel
        float hv = gacc[w * 5 + 4] * b1v;
#pragma unroll
        for (int kk = 0; kk < 4; ++kk) hv += gacc[w * 5 + kk] * w1v[kk];
        h[((size_t)(b * N + j0 + w)) * D + lane] = hv;
        hs[w][lane] = hv;
    }
    __syncthreads();
    if (t < 64) {
        float s = hs[0][lane] + hs[1][lane] + hs[2][lane] + hs[3][lane];
        float sq = hs[0][lane]*hs[0][lane] + hs[1][lane]*hs[1][lane]
                 + hs[2][lane]*hs[2][lane] + hs[3][lane]*hs[3][lane];
        atomicAdd(bnacc + lane, s);
        atomicAdd(bnacc + D + lane, sq);
    }
}

// ---------------------------------------------------------------------------
// P3: BN finalize + QKV layer 0. grid (B, N/2) = 512 blocks x 256 thr.
// Wave = k-quarter (split-K-4), weight-stationary over 2 tokens. Weights
// prefetched to registers at kernel entry (overlap BN loads).
// ---------------------------------------------------------------------------
__global__ void __launch_bounds__(256, 4) k_qkv0(
    const float* __restrict__ h, const float* __restrict__ bnacc,
    const float* __restrict__ bn_g, const float* __restrict__ bn_b,
    const float* __restrict__ Wq, const float* __restrict__ bq,
    const float* __restrict__ Wk, const float* __restrict__ bk,
    const float* __restrict__ Wv, const float* __restrict__ bv,
    float* __restrict__ x, float* __restrict__ q,
    float* __restrict__ k, float* __restrict__ v) {
    __shared__ float xs[2][D];
    __shared__ float pp[4][2][192];
    int t = threadIdx.x, lane = t & 63, w = t >> 6, ch = lane;
    int b = blockIdx.x, n0 = blockIdx.y * 2;

    // prefetch weights (registers, used after barrier)
    float wq[16], wk[16], wv[16];
#pragma unroll
    for (int i = 0; i < 16; ++i) {
        int kk = w * 16 + i;
        wq[i] = Wq[kk * D + ch];
        wk[i] = Wk[kk * D + ch];
        wv[i] = Wv[kk * D + ch];
    }
    float mean = bnacc[ch] * (1.0f / (B * N));
    float var = bnacc[D + ch] * (1.0f / (B * N)) - mean * mean;
    float inv = rsqrtf(var + EPS);
    size_t xi0 = ((size_t)(b * N + n0)) * D + ch;
    float xv0 = bn_g[ch] * (h[xi0] - mean) * inv + bn_b[ch];
    float xv1 = bn_g[ch] * (h[xi0 + D] - mean) * inv + bn_b[ch];
    if (w == 0) { x[xi0] = xv0; xs[0][ch] = xv0; }
    if (w == 1) { x[xi0 + D] = xv1; xs[1][ch] = xv1; }
    __syncthreads();

    float aq0=0.f, ak0=0.f, av0=0.f, aq1=0.f, ak1=0.f, av1=0.f;
#pragma unroll
    for (int i = 0; i < 16; ++i) {
        int kk = w * 16 + i;
        float xx0 = xs[0][kk], xx1 = xs[1][kk];
        aq0 += xx0 * wq[i]; ak0 += xx0 * wk[i]; av0 += xx0 * wv[i];
        aq1 += xx1 * wq[i]; ak1 += xx1 * wk[i]; av1 += xx1 * wv[i];
    }
    pp[w][0][ch] = aq0; pp[w][0][64 + ch] = ak0; pp[w][0][128 + ch] = av0;
    pp[w][1][ch] = aq1; pp[w][1][64 + ch] = ak1; pp[w][1][128 + ch] = av1;
    __syncthreads();
    if (w < 3) {
        int o = w * 64;
        int head = ch >> 4, dh = ch & (DH - 1);
#pragma unroll
        for (int tk = 0; tk < 2; ++tk) {
            float val = pp[0][tk][o+ch] + pp[1][tk][o+ch] + pp[2][tk][o+ch] + pp[3][tk][o+ch];
            size_t oidx = (((size_t)(b * NH + head)) * N + (n0 + tk)) * DH + dh;
            if (w == 0) q[oidx] = val + bq[ch];
            else if (w == 1) k[oidx] = val + bk[ch];
            else v[oidx] = val + bv[ch];
        }
    }
}

// ---------------------------------------------------------------------------
// Layer tail: attention + O-proj + LN1 + FFN + LN2 (+ next-layer QKV).
// grid (B, N/2) = 512 blocks x 256 thr. 2 tokens/block: weights register-
// stationary over both tokens (halved L2 traffic vs 1 token/block), each
// phase's weights prefetched during the previous phase's compute so no L2
// latency sits behind a barrier. LN stats computed redundantly per wave in
// registers. Attention: wave = head, K/V streamed in 64-key chunks, both
// queries share each chunk. No softmax max-subtract (scores bounded small).
// ---------------------------------------------------------------------------
template <bool FUSE>
__global__ void __launch_bounds__(256, 4) k_layer(
    const float* __restrict__ q, const float* __restrict__ k,
    const float* __restrict__ v,
    const float* __restrict__ Wo, const float* __restrict__ bo,
    const float* __restrict__ ln1g, const float* __restrict__ ln1b,
    const float* __restrict__ Wff1, const float* __restrict__ bff1,
    const float* __restrict__ Wff2, const float* __restrict__ bff2,
    const float* __restrict__ ln2g, const float* __restrict__ ln2b,
    const float* __restrict__ Wqn, const float* __restrict__ bqn,
    const float* __restrict__ Wkn, const float* __restrict__ bkn,
    const float* __restrict__ Wvn, const float* __restrict__ bvn,
    float* __restrict__ qo, float* __restrict__ ko, float* __restrict__ vo,
    float* __restrict__ x) {
    __shared__ float attS[2][D];
    __shared__ float xs[2][D];
    __shared__ float f1s[2][2 * D];
    __shared__ float ppA[4][2][192];
    __shared__ float ppB[4][2][192];
    int t = threadIdx.x, lane = t & 63, w = t >> 6, ch = lane;
    int b = blockIdx.x, n0 = blockIdx.y * 2;

    size_t xi0 = ((size_t)(b * N + n0)) * D + ch;
    float xv0 = x[xi0], xv1 = x[xi0 + D];
    // per-lane params, issued early
    float bo_r = bo[ch], l1g = ln1g[ch], l1b = ln1b[ch];
    float bf1a = bff1[ch], bf1b = bff1[D + ch];
    float bf2_r = bff2[ch], l2g = ln2g[ch], l2b = ln2b[ch];

    // ---- attention: wave = head; stream K/V in 4 chunks of 64 keys ----
    int bh = b * NH + w;
    const float4* qp0 = (const float4*)(q + ((size_t)bh * N + n0) * DH);
    const float4* qp1 = (const float4*)(q + ((size_t)bh * N + n0 + 1) * DH);
    float4 qv0[4], qv1[4];
#pragma unroll
    for (int c = 0; c < 4; ++c) { qv0[c] = qp0[c]; qv1[c] = qp1[c]; }
    const float* kb = k + (size_t)bh * N * DH;
    const float* vb = v + (size_t)bh * N * DH;
    float o0[DH], o1[DH];
#pragma unroll
    for (int d = 0; d < DH; ++d) { o0[d] = 0.f; o1[d] = 0.f; }
    float l0 = 0.f, l1 = 0.f;
#pragma unroll 1
    for (int cc = 0; cc < 4; ++cc) {
        int key = cc * 64 + lane;
        const float4* kp4 = (const float4*)(kb + (size_t)key * DH);
        const float4* vp4 = (const float4*)(vb + (size_t)key * DH);
        float4 Kc[4], Vc[4];
#pragma unroll
        for (int c = 0; c < 4; ++c) { Kc[c] = kp4[c]; Vc[c] = vp4[c]; }
        float s0 = 0.f, s1 = 0.f;
#pragma unroll
        for (int c = 0; c < 4; ++c) {
            s0 += qv0[c].x * Kc[c].x + qv0[c].y * Kc[c].y +
                  qv0[c].z * Kc[c].z + qv0[c].w * Kc[c].w;
            s1 += qv1[c].x * Kc[c].x + qv1[c].y * Kc[c].y +
                  qv1[c].z * Kc[c].z + qv1[c].w * Kc[c].w;
        }
        float p0 = __expf(s0 * 0.25f);
        float p1 = __expf(s1 * 0.25f);
        l0 += p0; l1 += p1;
#pragma unroll
        for (int c = 0; c < 4; ++c) {
            o0[4*c+0] += p0 * Vc[c].x; o0[4*c+1] += p0 * Vc[c].y;
            o0[4*c+2] += p0 * Vc[c].z; o0[4*c+3] += p0 * Vc[c].w;
            o1[4*c+0] += p1 * Vc[c].x; o1[4*c+1] += p1 * Vc[c].y;
            o1[4*c+2] += p1 * Vc[c].z; o1[4*c+3] += p1 * Vc[c].w;
        }
    }
    // prefetch Wo while the reductions run
    float wo[16];
#pragma unroll
    for (int i = 0; i < 16; ++i) wo[i] = Wo[(w * 16 + i) * D + ch];

#pragma unroll
    for (int off = 32; off > 0; off >>= 1) {
        l0 += __shfl_xor(l0, off);
        l1 += __shfl_xor(l1, off);
    }
#pragma unroll
    for (int d = 0; d < DH; ++d) {
#pragma unroll
        for (int off = 32; off > 0; off >>= 1) {
            o0[d] += __shfl_xor(o0[d], off);
            o1[d] += __shfl_xor(o1[d], off);
        }
    }
    float rl0 = 1.f / l0, rl1 = 1.f / l1;
    if (lane < DH) {
        float sel0 = o0[0], sel1 = o1[0];
#pragma unroll
        for (int d = 1; d < DH; ++d)
            if (lane == d) { sel0 = o0[d]; sel1 = o1[d]; }
        attS[0][w * DH + lane] = sel0 * rl0;
        attS[1][w * DH + lane] = sel1 * rl1;
    }
    __syncthreads();

    // ---- O-proj (split-K-4, both tokens) + prefetch Wff1 ----
    {
        float a0 = 0.f, a1 = 0.f;
#pragma unroll
        for (int i = 0; i < 16; ++i) {
            int kk = w * 16 + i;
            float wv = wo[i];
            a0 += attS[0][kk] * wv;
            a1 += attS[1][kk] * wv;
        }
        ppA[w][0][ch] = a0; ppA[w][1][ch] = a1;
    }
    float wf1a[16], wf1b[16];
#pragma unroll
    for (int i = 0; i < 16; ++i) {
        int kk = w * 16 + i;
        wf1a[i] = Wff1[kk * 2 * D + ch];
        wf1b[i] = Wff1[kk * 2 * D + D + ch];
    }
    __syncthreads();

    // ---- LN1 (both tokens, redundant per wave) ----
    float r0 = xv0 + bo_r + ppA[0][0][ch] + ppA[1][0][ch] + ppA[2][0][ch] + ppA[3][0][ch];
    float r1 = xv1 + bo_r + ppA[0][1][ch] + ppA[1][1][ch] + ppA[2][1][ch] + ppA[3][1][ch];
    float s0a = r0, q0a = r0 * r0, s1a = r1, q1a = r1 * r1;
#pragma unroll
    for (int off = 32; off > 0; off >>= 1) {
        s0a += __shfl_xor(s0a, off); q0a += __shfl_xor(q0a, off);
        s1a += __shfl_xor(s1a, off); q1a += __shfl_xor(q1a, off);
    }
    float mean10 = s0a * (1.0f / D), var10 = q0a * (1.0f / D) - mean10 * mean10;
    float mean11 = s1a * (1.0f / D), var11 = q1a * (1.0f / D) - mean11 * mean11;
    float x1_0 = l1g * (r0 - mean10) * rsqrtf(var10 + EPS) + l1b;
    float x1_1 = l1g * (r1 - mean11) * rsqrtf(var11 + EPS) + l1b;
    if (w == 0) xs[0][ch] = x1_0;
    if (w == 1) xs[1][ch] = x1_1;
    __syncthreads();

    // ---- FFN1 (split-K-4, both halves, both tokens) + prefetch Wff2 ----
    {
        float u0=0.f, g0=0.f, u1=0.f, g1=0.f;
#pragma unroll
        for (int i = 0; i < 16; ++i) {
            int kk = w * 16 + i;
            float xx0 = xs[0][kk], xx1 = xs[1][kk];
            u0 += xx0 * wf1a[i]; g0 += xx0 * wf1b[i];
            u1 += xx1 * wf1a[i]; g1 += xx1 * wf1b[i];
        }
        ppB[w][0][ch] = u0; ppB[w][0][64 + ch] = g0;
        ppB[w][1][ch] = u1; ppB[w][1][64 + ch] = g1;
    }
    float wf2[32];
#pragma unroll
    for (int i = 0; i < 32; ++i) wf2[i] = Wff2[(w * 32 + i) * D + ch];
    __syncthreads();

    // ---- ReLU combine -> f1s ----
    {
        float a00 = fmaxf(bf1a + ppB[0][0][ch] + ppB[1][0][ch] + ppB[2][0][ch] + ppB[3][0][ch], 0.f);
        float a01 = fmaxf(bf1b + ppB[0][0][64+ch] + ppB[1][0][64+ch] + ppB[2][0][64+ch] + ppB[3][0][64+ch], 0.f);
        float a10 = fmaxf(bf1a + ppB[0][1][ch] + ppB[1][1][ch] + ppB[2][1][ch] + ppB[3][1][ch], 0.f);
        float a11 = fmaxf(bf1b + ppB[0][1][64+ch] + ppB[1][1][64+ch] + ppB[2][1][64+ch] + ppB[3][1][64+ch], 0.f);
        if (w == 0) { f1s[0][ch] = a00; f1s[0][64 + ch] = a01; }
        if (w == 1) { f1s[1][ch] = a10; f1s[1][64 + ch] = a11; }
    }
    __syncthreads();

    // ---- FFN2 (split-K-4 over 128, both tokens) + prefetch next QKV ----
    {
        float e0 = 0.f, e1 = 0.f;
#pragma unroll
        for (int i = 0; i < 32; ++i) {
            int kk = w * 32 + i;
            float xx0 = f1s[0][kk], xx1 = f1s[1][kk];
            e0 += xx0 * wf2[i];
            e1 += xx1 * wf2[i];
        }
        ppA[w][0][ch] = e0; ppA[w][1][ch] = e1;
    }
    float wqn[16], wkn[16], wvn[16];
    if (FUSE) {
#pragma unroll
        for (int i = 0; i < 16; ++i) {
            int kk = w * 16 + i;
            wqn[i] = Wqn[kk * D + ch];
            wkn[i] = Wkn[kk * D + ch];
            wvn[i] = Wvn[kk * D + ch];
        }
    }
    __syncthreads();

    // ---- LN2 (both tokens, redundant per wave) ----
    float o2_0 = bf2_r + ppA[0][0][ch] + ppA[1][0][ch] + ppA[2][0][ch] + ppA[3][0][ch];
    float o2_1 = bf2_r + ppA[0][1][ch] + ppA[1][1][ch] + ppA[2][1][ch] + ppA[3][1][ch];
    float r20 = x1_0 + o2_0, r21 = x1_1 + o2_1;
    float s0b = r20, q0b = r20 * r20, s1b = r21, q1b = r21 * r21;
#pragma unroll
    for (int off = 32; off > 0; off >>= 1) {
        s0b += __shfl_xor(s0b, off); q0b += __shfl_xor(q0b, off);
        s1b += __shfl_xor(s1b, off); q1b += __shfl_xor(q1b, off);
    }
    float mean20 = s0b * (1.0f / D), var20 = q0b * (1.0f / D) - mean20 * mean20;
    float mean21 = s1b * (1.0f / D), var21 = q1b * (1.0f / D) - mean21 * mean21;
    float xn0 = l2g * (r20 - mean20) * rsqrtf(var20 + EPS) + l2b;
    float xn1 = l2g * (r21 - mean21) * rsqrtf(var21 + EPS) + l2b;
    if (w == 0) x[xi0] = xn0;
    if (w == 1) x[xi0 + D] = xn1;

    // ---- fused next-layer QKV ----
    if (FUSE) {
        if (w == 0) xs[0][ch] = xn0;
        if (w == 1) xs[1][ch] = xn1;
        __syncthreads();
        float aq0=0.f, ak0=0.f, av0=0.f, aq1=0.f, ak1=0.f, av1=0.f;
#pragma unroll
        for (int i = 0; i < 16; ++i) {
            int kk = w * 16 + i;
            float xx0 = xs[0][kk], xx1 = xs[1][kk];
            aq0 += xx0 * wqn[i]; ak0 += xx0 * wkn[i]; av0 += xx0 * wvn[i];
            aq1 += xx1 * wqn[i]; ak1 += xx1 * wkn[i]; av1 += xx1 * wvn[i];
        }
        ppB[w][0][ch] = aq0; ppB[w][0][64 + ch] = ak0; ppB[w][0][128 + ch] = av0;
        ppB[w][1][ch] = aq1; ppB[w][1][64 + ch] = ak1; ppB[w][1][128 + ch] = av1;
        __syncthreads();
        if (w < 3) {
            int o = w * 64;
            int head = ch >> 4, dh = ch & (DH - 1);
#pragma unroll
            for (int tk = 0; tk < 2; ++tk) {
                float val = ppB[0][tk][o+ch] + ppB[1][tk][o+ch] + ppB[2][tk][o+ch] + ppB[3][tk][o+ch];
                size_t oidx = (((size_t)(b * NH + head)) * N + (n0 + tk)) * DH + dh;
                if (w == 0) qo[oidx] = val + bqn[ch];
                else if (w == 1) ko[oidx] = val + bkn[ch];
                else vo[oidx] = val + bvn[ch];
            }
        }
    }
}

extern "C" void kernel_launch(void* const* d_in, const int* in_sizes, int n_in,
                              void* d_out, int out_size, void* d_ws, size_t ws_size,
                              hipStream_t stream) {
    const float* feature = (const float*)d_in[0];
    const float* W1   = (const float*)d_in[1];
    const float* b1   = (const float*)d_in[2];
    const float* mw   = (const float*)d_in[3];
    const float* mb   = (const float*)d_in[4];
    const float* bn_g = (const float*)d_in[5];
    const float* bn_b = (const float*)d_in[6];
    const float* Wq   = (const float*)d_in[7];
    const float* bq   = (const float*)d_in[8];
    const float* Wk   = (const float*)d_in[9];
    const float* bk   = (const float*)d_in[10];
    const float* Wv   = (const float*)d_in[11];
    const float* bv   = (const float*)d_in[12];
    const float* Wo   = (const float*)d_in[13];
    const float* bo   = (const float*)d_in[14];
    const float* ln1g = (const float*)d_in[15];
    const float* ln1b = (const float*)d_in[16];
    const float* Wff1 = (const float*)d_in[17];
    const float* bff1 = (const float*)d_in[18];
    const float* Wff2 = (const float*)d_in[19];
    const float* bff2 = (const float*)d_in[20];
    const float* ln2g = (const float*)d_in[21];
    const float* ln2b = (const float*)d_in[22];

    float* ws    = (float*)d_ws;
    float* rs    = ws;                     // B*N*NH = 4096
    float* bnacc = rs + B * N * NH;        // 128
    float* h     = bnacc + 128;            // B*N*D
    float* q     = h + B * N * D;          // B*N*D
    float* k0    = q + B * N * D;
    float* v0    = k0 + B * N * D;
    float* k1    = v0 + B * N * D;
    float* v1    = k1 + B * N * D;
    float* x     = (float*)d_out;          // running (B,N,D) activation

    k_rowsum<<<256, 512, 0, stream>>>(feature, W1, b1, mw, mb, rs, bnacc);
    k_aggregate<<<256, 512, 0, stream>>>(feature, W1, b1, mw, mb, rs, h, bnacc);
    k_qkv0<<<dim3(B, N / 2), 256, 0, stream>>>(h, bnacc, bn_g, bn_b,
                                               Wq, bq, Wk, bk, Wv, bv, x, q, k0, v0);
    // layer 0 (fused layer-1 QKV into q / k1 / v1), then layer 1
    k_layer<true><<<dim3(B, N / 2), 256, 0, stream>>>(q, k0, v0,
        Wo, bo, ln1g, ln1b, Wff1, bff1, Wff2, bff2, ln2g, ln2b,
        Wq + (size_t)D * D, bq + D, Wk + (size_t)D * D, bk + D,
        Wv + (size_t)D * D, bv + D, q, k1, v1, x);
    k_layer<false><<<dim3(B, N / 2), 256, 0, stream>>>(q, k1, v1,
        Wo + (size_t)D * D, bo + D, ln1g + D, ln1b + D,
        Wff1 + (size_t)D * 2 * D, bff1 + 2 * D,
        Wff2 + (size_t)2 * D * D, bff2 + D, ln2g + D, ln2b + D,
        nullptr, nullptr, nullptr, nullptr, nullptr, nullptr,
        nullptr, nullptr, nullptr, x);
}